// Round 7
// baseline (302.554 us; speedup 1.0000x reference)
//
#include <hip/hip_runtime.h>

// MultiHeadSelfAttention: B=4, S=2048, D=1024, H=16, HD=64, causal. fp32 I/O, bf16 MFMA.
// R15 = R14 with attn split into TWO balanced 512-block dispatches (bh 0-31 / 32-63).
// INSTRUMENTATION ROUND: three different GEMM structures (R10/R13/R14) gave identical
// totals, and Delta(total)==Delta(attn) across rounds -> non-attn is a stable 188 us we
// have never directly measured (top-5 only shows attn at ~81, bounding GEMMs < 81).
// Splitting attn to ~43 us/half forces any GEMM dispatch > 43 us into the top-5 WITH
// counters. Cost ~+6 us (halves run at 2 blocks/CU). Balance: s=bid&7, hi=bid>>8,
// qt = hi ? 15-2s : 2s -> co-resident pair (2s, 15-2s) = 34 units on every CU, all
// blocks resident at t=0. base_bh is a runtime arg (no template codegen perturbation).
// GEMMs/casts byte-identical to R14.

typedef short s16;
typedef __attribute__((ext_vector_type(4))) short s16x4;
typedef __attribute__((ext_vector_type(8))) short bf16x8;
typedef __attribute__((ext_vector_type(4))) float f32x4;

__device__ __forceinline__ s16 f2bf(float f) {
    union { float f; unsigned int i; } v;
    v.f = f;
    unsigned int r = v.i + 0x7fffu + ((v.i >> 16) & 1u);  // RNE
    return (s16)(r >> 16);
}

// pack two fp32 -> bf16x2 dword (round-half-up)
__device__ __forceinline__ unsigned pack_bf16(float a, float b) {
    union { float f; unsigned u; } x, y;
    x.f = a; y.f = b;
    return __byte_perm(x.u + 0x8000u, y.u + 0x8000u, 0x7632);
}

__device__ __forceinline__ void load_lds16(const s16* g, s16* lds_base) {
    __builtin_amdgcn_global_load_lds(
        (const __attribute__((address_space(1))) void*)g,
        (__attribute__((address_space(3))) void*)lds_base, 16, 0, 0);
}

// ---------------------------------------------------------------------------
// fp32 -> bf16 elementwise cast
// ---------------------------------------------------------------------------
__global__ void cast_f32_bf16(const float* __restrict__ in, s16* __restrict__ out) {
    const int i = (blockIdx.x * 256 + threadIdx.x) * 4;
    const float4 f = *(const float4*)(in + i);
    s16x4 r = {f2bf(f.x), f2bf(f.y), f2bf(f.z), f2bf(f.w)};
    *(s16x4*)(out + i) = r;
}

// ---------------------------------------------------------------------------
// Transpose + cast: fp32 [R,C] -> bf16 [C,R]
// ---------------------------------------------------------------------------
__global__ void transpose_cast(const float* __restrict__ in,
                               s16* __restrict__ out, int R, int C) {
    __shared__ float tile[32][33];
    const int cb = blockIdx.x * 32, rb = blockIdx.y * 32;
    const int tx = threadIdx.x, ty = threadIdx.y;  // 32 x 8
#pragma unroll
    for (int i = 0; i < 32; i += 8)
        tile[ty + i][tx] = in[(size_t)(rb + ty + i) * C + cb + tx];
    __syncthreads();
#pragma unroll
    for (int i = 0; i < 32; i += 8)
        out[(size_t)(cb + ty + i) * R + rb + tx] = f2bf(tile[tx][ty + i]);
}

// ---------------------------------------------------------------------------
// C[M,N] = A[M,K] @ Bt[N,K]^T + bias[N]. A,Bt bf16; C fp32 or bf16.
// 256x256 tile, BK=64, 8 waves (2Mx4N, 128x64/wave). Flat grid (nwg%8==0), gx =
// N-tiles. Requires M%256==0, N%256==0, K%64==0. (R14, correctness-proven)
// ---------------------------------------------------------------------------
template <bool OUT_F32>
__global__ __launch_bounds__(512, 2) void gemm_bt_bias_256(
    const s16* __restrict__ A,
    const s16* __restrict__ Bt,
    const float* __restrict__ bias,
    void* __restrict__ Cv,
    int M, int N, int K, int gx) {
    __shared__ __attribute__((aligned(16))) s16 As[2][256 * 64];
    __shared__ __attribute__((aligned(16))) s16 Bs[2][256 * 64];

    const int tid  = threadIdx.x;
    const int lane = tid & 63;
    const int wave = tid >> 6;   // 0..7
    const int l15  = lane & 15;
    const int quad = lane >> 4;
    const int wr   = wave >> 2;  // 0..1 (M half, 128 rows)
    const int wc   = wave & 3;   // 0..3 (N quarter, 64 cols)

    // T1: XCD-bijective swizzle (nwg % 8 == 0 for both call sites)
    const int cpx = (int)gridDim.x >> 3;
    const int bid = (int)blockIdx.x;
    const int swz = (bid & 7) * cpx + (bid >> 3);
    const int m0 = (swz / gx) * 256;
    const int n0 = (swz % gx) * 256;

    // staging: thread = (srow = tid>>3 of a 64-row chunk, granule tid&7);
    // source granule pre-swizzled (g ^ (row&7)); LDS dest linear (both-sides rule).
    const int srow = tid >> 3;
    const int sg   = (tid & 7) ^ (srow & 7);
    const s16* Ag = A  + (size_t)(m0 + srow) * K + sg * 8;
    const s16* Bg = Bt + (size_t)(n0 + srow) * K + sg * 8;

#define STG(buf, c, kt) do {                                                        \
    load_lds16(Ag + (size_t)(c) * 64 * K + (size_t)(kt) * 64,                       \
               &As[buf][(c) * 4096 + wave * 512]);                                  \
    load_lds16(Bg + (size_t)(c) * 64 * K + (size_t)(kt) * 64,                       \
               &Bs[buf][(c) * 4096 + wave * 512]); } while (0)

    f32x4 acc[8][4];
#pragma unroll
    for (int i = 0; i < 8; ++i)
#pragma unroll
        for (int j = 0; j < 4; ++j)
            acc[i][j] = (f32x4){0.f, 0.f, 0.f, 0.f};

    const int nk = K >> 6;

    // prologue: stage tile 0 (all 4 chunk-pairs), drain, sync
    STG(0, 0, 0); STG(0, 1, 0); STG(0, 2, 0); STG(0, 3, 0);
    __syncthreads();

    for (int t = 0; t < nk; ++t) {
        const int buf  = t & 1;
        const int nbuf = buf ^ 1;
        const bool pre = (t + 1 < nk);
        bf16x8 bfr[4][2];  // B-frags held across the 4 phases of this K-tile
#pragma unroll
        for (int q = 0; q < 4; ++q) {
            if (q == 0) {
#pragma unroll
                for (int n = 0; n < 4; ++n)
#pragma unroll
                    for (int ks = 0; ks < 2; ++ks) {
                        const int br = wc * 64 + n * 16 + l15;
                        const int gs = ((ks * 4 + quad) ^ (l15 & 7)) * 8;
                        bfr[n][ks] = *(const bf16x8*)(&Bs[buf][br * 64 + gs]);
                    }
            }
            bf16x8 af[2][2];
#pragma unroll
            for (int i = 0; i < 2; ++i)
#pragma unroll
                for (int ks = 0; ks < 2; ++ks) {
                    const int ar = wr * 128 + (q * 2 + i) * 16 + l15;
                    const int gs = ((ks * 4 + quad) ^ (l15 & 7)) * 8;
                    af[i][ks] = *(const bf16x8*)(&As[buf][ar * 64 + gs]);
                }
            // issue next tile's staging early (phases 0-1): 2-3 phases old at drain
            if (q == 0 && pre) { STG(nbuf, 0, t + 1); STG(nbuf, 1, t + 1); }
            if (q == 1 && pre) { STG(nbuf, 2, t + 1); STG(nbuf, 3, t + 1); }
            __builtin_amdgcn_s_barrier();  // phase-align waves
            __builtin_amdgcn_s_setprio(1);
#pragma unroll
            for (int i = 0; i < 2; ++i)
#pragma unroll
                for (int n = 0; n < 4; ++n)
#pragma unroll
                    for (int ks = 0; ks < 2; ++ks)
                        acc[q * 2 + i][n] = __builtin_amdgcn_mfma_f32_16x16x32_bf16(
                            af[i][ks], bfr[n][ks], acc[q * 2 + i][n], 0, 0, 0);
            __builtin_amdgcn_s_setprio(0);
            if (q == 3)
                __syncthreads();  // tile boundary: drain staged loads + sync
            else
                __builtin_amdgcn_s_barrier();
        }
    }
#undef STG

    // epilogue: wave writes its 128x64 block
#pragma unroll
    for (int n = 0; n < 4; ++n) {
        const int col = n0 + wc * 64 + n * 16 + l15;
        const float bv = bias[col];
#pragma unroll
        for (int mf = 0; mf < 8; ++mf) {
            const int rowb = m0 + wr * 128 + mf * 16 + quad * 4;
#pragma unroll
            for (int r = 0; r < 4; ++r) {
                const float v = acc[mf][n][r] + bv;
                if constexpr (OUT_F32)
                    ((float*)Cv)[(size_t)(rowb + r) * N + col] = v;
                else
                    ((s16*)Cv)[(size_t)(rowb + r) * N + col] = f2bf(v);
            }
        }
    }
}

// ---------------------------------------------------------------------------
// Flash attention (causal), fixed-M softmax, S^T formulation. (R10/R13/R14 proven)
// HALF grid: 512 blocks covering bh in [base_bh, base_bh+32) x all 16 q-tiles.
// Decode: s=bid&7, bh=base_bh+((bid>>3)&31), hi=bid>>8; qt = hi ? 15-2s : 2s.
// Co-resident CU pair (bid, bid+256): qt pair (2s, 15-2s) -> 34 units per CU,
// all 512 blocks resident at t=0 (2 blocks/CU).
// ---------------------------------------------------------------------------
__global__ __launch_bounds__(256) void attn_fwd(
    const s16* __restrict__ qkv,
    s16* __restrict__ attn,
    int base_bh) {
    __shared__ __attribute__((aligned(16))) s16 Ks[64 * 72];
    __shared__ __attribute__((aligned(16))) s16 Vt[64 * 72];
    __shared__ __attribute__((aligned(16))) s16 PT[4][32][88];

    const int tid  = threadIdx.x;
    const int lane = tid & 63;
    const int wave = tid >> 6;
    const int l15  = lane & 15;
    const int quad = lane >> 4;

    // balanced (bh, qt) decomposition for the 512-block half (see header comment)
    const int bid = blockIdx.x;
    const int hi  = bid >> 8;               // 0..1
    const int s   = bid & 7;                // qt slot
    const int bh  = base_bh + ((bid >> 3) & 31);
    const int qt  = hi ? 15 - 2 * s : 2 * s;

    const size_t rowbase = (size_t)(bh >> 4) * 2048;
    const int hoff = (bh & 15) * 64;
    const int kp  = tid >> 3;  // 0..31: staged key-pair {2kp, 2kp+1}
    const int p_s = tid & 7;   // hd granule
    const int kg  = kp >> 2;   // key granule of this thread's pair

    const float C2 = 0.18033688011112042f;  // 0.125 * log2(e)
    const float M2 = 12.0f;                 // fixed shift (softmax shift-invariant)

    const int wq = qt * 128 + wave * 32;

    // Q fragments: lane holds Q[q = wq + qs*16 + l15][d = ks*32 + quad*8 + j]
    bf16x8 qf[2][2];
#pragma unroll
    for (int qs = 0; qs < 2; ++qs)
#pragma unroll
        for (int ks = 0; ks < 2; ++ks)
            qf[qs][ks] = *(const bf16x8*)(qkv + (rowbase + wq + qs * 16 + l15) * 3072 + hoff + ks * 32 + quad * 8);

    float l_lane[2] = {0.f, 0.f};
    f32x4 o[2][4];  // [qs][hs]; C-layout: q-col = l15, hd-row = hs*16 + quad*4 + r
#pragma unroll
    for (int qs = 0; qs < 2; ++qs)
#pragma unroll
        for (int hs = 0; hs < 4; ++hs)
            o[qs][hs] = (f32x4){0.f, 0.f, 0.f, 0.f};

    const int nkt = qt * 2 + 2;
    // prefetch tile 0 K/V
    bf16x8 kv[2], vv[2];
#pragma unroll
    for (int dk = 0; dk < 2; ++dk) {
        const s16* g = qkv + (rowbase + 2 * kp + dk) * 3072 + hoff + p_s * 8;
        kv[dk] = *(const bf16x8*)(g + 1024);
        vv[dk] = *(const bf16x8*)(g + 2048);
    }

    for (int kt = 0; kt < nkt; ++kt) {
        const int k0 = kt * 64;
        __syncthreads();  // prev iteration's LDS reads done
#pragma unroll
        for (int dk = 0; dk < 2; ++dk)  // K natural layout (R5-proven)
            *(bf16x8*)(Ks + (2 * kp + dk) * 72 + p_s * 8) = kv[dk];
#pragma unroll
        for (int j = 0; j < 8; ++j) {   // V^T swizzled, key-pair b32 (R7-verified)
            const unsigned dw = (unsigned)(unsigned short)vv[0][j] |
                                ((unsigned)(unsigned short)vv[1][j] << 16);
            *(unsigned*)(Vt + (p_s * 8 + j) * 72 + ((kg ^ p_s) << 3) + (2 * kp & 7)) = dw;
        }
        __syncthreads();

        if (kt + 1 < nkt) {  // prefetch next tile under compute
#pragma unroll
            for (int dk = 0; dk < 2; ++dk) {
                const s16* g = qkv + (rowbase + k0 + 64 + 2 * kp + dk) * 3072 + hoff + p_s * 8;
                kv[dk] = *(const bf16x8*)(g + 1024);
                vv[dk] = *(const bf16x8*)(g + 2048);
            }
        }

        if (k0 > wq + 31) continue;  // fully masked for this wave

        // S^T = K Q^T : st[qs][kb], key subtiles kb of 16
        f32x4 st[2][4];
#pragma unroll
        for (int qs = 0; qs < 2; ++qs)
#pragma unroll
            for (int kb = 0; kb < 4; ++kb)
                st[qs][kb] = (f32x4){0.f, 0.f, 0.f, 0.f};
        __builtin_amdgcn_s_setprio(1);
#pragma unroll
        for (int kb = 0; kb < 4; ++kb)
#pragma unroll
            for (int ks = 0; ks < 2; ++ks) {
                const bf16x8 kf = *(const bf16x8*)(Ks + (kb * 16 + l15) * 72 + ks * 32 + quad * 8);
#pragma unroll
                for (int qs = 0; qs < 2; ++qs)
                    st[qs][kb] = __builtin_amdgcn_mfma_f32_16x16x32_bf16(kf, qf[qs][ks], st[qs][kb], 0, 0, 0);
            }
        __builtin_amdgcn_s_setprio(0);

        // softmax (fixed-M) + P^T -> PT (b64, conflict-free)
        const bool edge = (k0 + 63 > wq);
#pragma unroll
        for (int qs = 0; qs < 2; ++qs) {
            const int q = wq + qs * 16 + l15;
#pragma unroll
            for (int kb = 0; kb < 4; ++kb) {
                float p4[4];
#pragma unroll
                for (int r = 0; r < 4; ++r) {
                    float t = fmaf(st[qs][kb][r], C2, -M2);
                    if (edge) {
                        const int key = k0 + kb * 16 + quad * 4 + r;
                        t = (key <= q) ? t : -150.f;  // exp2(-150) == 0
                    }
                    p4[r] = __builtin_amdgcn_exp2f(t);
                    l_lane[qs] += p4[r];
                }
                uint2 dd;
                dd.x = pack_bf16(p4[0], p4[1]);
                dd.y = pack_bf16(p4[2], p4[3]);
                *(uint2*)(&PT[wave][qs * 16 + l15][kb * 16 + quad * 4]) = dd;
            }
        }

        // O^T += V^T P^T
        __builtin_amdgcn_s_setprio(1);
#pragma unroll
        for (int kk = 0; kk < 2; ++kk) {
            bf16x8 pf[2];
#pragma unroll
            for (int qs = 0; qs < 2; ++qs)
                pf[qs] = *(const bf16x8*)(&PT[wave][qs * 16 + l15][kk * 32 + quad * 8]);
#pragma unroll
            for (int hs = 0; hs < 4; ++hs) {
                const bf16x8 vf = *(const bf16x8*)(
                    Vt + (hs * 16 + l15) * 72 + (((kk * 4 + quad) ^ (2 * hs + (l15 >> 3))) << 3));
#pragma unroll
                for (int qs = 0; qs < 2; ++qs)
                    o[qs][hs] = __builtin_amdgcn_mfma_f32_16x16x32_bf16(vf, pf[qs], o[qs][hs], 0, 0, 0);
            }
        }
        __builtin_amdgcn_s_setprio(0);
    }

    // l: sum across the 4 quads (lanes with same l15)
    float rl[2];
#pragma unroll
    for (int qs = 0; qs < 2; ++qs) {
        float l = l_lane[qs];
        l += __shfl_xor(l, 16);
        l += __shfl_xor(l, 32);
        rl[qs] = 1.f / l;
    }

    // epilogue: O^T[hd][q] -> attn[q][hoff+hd]; 4 consecutive hd per reg-quad -> b64
#pragma unroll
    for (int qs = 0; qs < 2; ++qs) {
        const int q = wq + qs * 16 + l15;
#pragma unroll
        for (int hs = 0; hs < 4; ++hs) {
            uint2 dd;
            dd.x = pack_bf16(o[qs][hs][0] * rl[qs], o[qs][hs][1] * rl[qs]);
            dd.y = pack_bf16(o[qs][hs][2] * rl[qs], o[qs][hs][3] * rl[qs]);
            *(uint2*)(attn + (rowbase + q) * 1024 + hoff + hs * 16 + quad * 4) = dd;
        }
    }
}

// ---------------------------------------------------------------------------
extern "C" void kernel_launch(void* const* d_in, const int* in_sizes, int n_in,
                              void* d_out, int out_size, void* d_ws, size_t ws_size,
                              hipStream_t stream) {
    const float* x    = (const float*)d_in[0];  // [8192,1024]
    const float* Wqkv = (const float*)d_in[1];  // [1024,3072]
    const float* bqkv = (const float*)d_in[2];  // [3072]
    const float* Wout = (const float*)d_in[3];  // [1024,1024]
    const float* bout = (const float*)d_in[4];  // [1024]
    float* out = (float*)d_out;                 // [8192,1024] fp32

    s16* ws   = (s16*)d_ws;
    s16* qkv  = ws;                          // [8192,3072] bf16
    s16* xba  = qkv + (size_t)8192 * 3072;   // [8192,1024] bf16: x-cast, later attn output
    s16* wtq  = xba + (size_t)8192 * 1024;   // [3072,1024] bf16
    s16* wto  = wtq + (size_t)3072 * 1024;   // [1024,1024] bf16

    cast_f32_bf16<<<8192, 256, 0, stream>>>(x, xba);
    transpose_cast<<<dim3(3072 / 32, 1024 / 32), dim3(32, 8), 0, stream>>>(Wqkv, wtq, 1024, 3072);
    transpose_cast<<<dim3(1024 / 32, 1024 / 32), dim3(32, 8), 0, stream>>>(Wout, wto, 1024, 1024);
    gemm_bt_bias_256<false><<<384, 512, 0, stream>>>(
        xba, wtq, bqkv, qkv, 8192, 3072, 1024, 12);
    attn_fwd<<<512, 256, 0, stream>>>(qkv, xba, 0);   // bh 0..31
    attn_fwd<<<512, 256, 0, stream>>>(qkv, xba, 32);  // bh 32..63
    gemm_bt_bias_256<true><<<128, 512, 0, stream>>>(
        xba, wto, bout, out, 8192, 1024, 1024, 4);
}

// Round 8
// 274.482 us; speedup vs baseline: 1.1023x; 1.1023x over previous
//
#include <hip/hip_runtime.h>

// MultiHeadSelfAttention: B=4, S=2048, D=1024, H=16, HD=64, causal. fp32 I/O, bf16 MFMA.
// R16 = R14 attn (1024-block, 81 us proven; R15's split instrumentation reverted) +
// GEMM counted-vmcnt fix. R15 counters for the 256^2 GEMM: 77 us / 670 TF, MfmaUtil 26,
// VALUBusy 15, bank-conflict 0 -> stalled on the per-tile __syncthreads = vmcnt(0) drain
// of loads issued only ~2 phases earlier (m218: counted-vs-drain0 = +38%).
// Changes vs R14 (GEMM only):
//  1. Stage order B0,B1,B2,B3 / A0,A2,A1,A3; per-tile waits: q1-end vmcnt(8) (frees
//     A1,A3 needed at q2; ~6 phases old = free), q3-end vmcnt(2) (B+A0,A2 of next tile
//     landed; A1,A3 stay in flight ACROSS the boundary). Waits BEFORE barriers so the
//     barrier collects every wave's drain. Last tile: vmcnt(0) tail.
//  2. Store loops reordered row-contiguous (mf,r outer, n inner; bias hoisted):
//     4 back-to-back 32B segments complete each 128B line -> fewer partial writebacks
//     (R15: WRITE_SIZE 83 MB vs 48 ideal).
// Known-accepted: 384 blocks at 1 block/CU (128KB LDS) = 2 rounds, round 2 half idle.

typedef short s16;
typedef __attribute__((ext_vector_type(4))) short s16x4;
typedef __attribute__((ext_vector_type(8))) short bf16x8;
typedef __attribute__((ext_vector_type(4))) float f32x4;

__device__ __forceinline__ s16 f2bf(float f) {
    union { float f; unsigned int i; } v;
    v.f = f;
    unsigned int r = v.i + 0x7fffu + ((v.i >> 16) & 1u);  // RNE
    return (s16)(r >> 16);
}

// pack two fp32 -> bf16x2 dword (round-half-up)
__device__ __forceinline__ unsigned pack_bf16(float a, float b) {
    union { float f; unsigned u; } x, y;
    x.f = a; y.f = b;
    return __byte_perm(x.u + 0x8000u, y.u + 0x8000u, 0x7632);
}

__device__ __forceinline__ void load_lds16(const s16* g, s16* lds_base) {
    __builtin_amdgcn_global_load_lds(
        (const __attribute__((address_space(1))) void*)g,
        (__attribute__((address_space(3))) void*)lds_base, 16, 0, 0);
}

// ---------------------------------------------------------------------------
// fp32 -> bf16 elementwise cast
// ---------------------------------------------------------------------------
__global__ void cast_f32_bf16(const float* __restrict__ in, s16* __restrict__ out) {
    const int i = (blockIdx.x * 256 + threadIdx.x) * 4;
    const float4 f = *(const float4*)(in + i);
    s16x4 r = {f2bf(f.x), f2bf(f.y), f2bf(f.z), f2bf(f.w)};
    *(s16x4*)(out + i) = r;
}

// ---------------------------------------------------------------------------
// Transpose + cast: fp32 [R,C] -> bf16 [C,R]
// ---------------------------------------------------------------------------
__global__ void transpose_cast(const float* __restrict__ in,
                               s16* __restrict__ out, int R, int C) {
    __shared__ float tile[32][33];
    const int cb = blockIdx.x * 32, rb = blockIdx.y * 32;
    const int tx = threadIdx.x, ty = threadIdx.y;  // 32 x 8
#pragma unroll
    for (int i = 0; i < 32; i += 8)
        tile[ty + i][tx] = in[(size_t)(rb + ty + i) * C + cb + tx];
    __syncthreads();
#pragma unroll
    for (int i = 0; i < 32; i += 8)
        out[(size_t)(cb + ty + i) * R + rb + tx] = f2bf(tile[tx][ty + i]);
}

// ---------------------------------------------------------------------------
// C[M,N] = A[M,K] @ Bt[N,K]^T + bias[N]. A,Bt bf16; C fp32 or bf16.
// 256x256 tile, BK=64, 8 waves (2Mx4N, 128x64/wave), counted-vmcnt pipeline.
// Flat grid (nwg%8==0), gx = N-tiles. Requires M%256==0, N%256==0, K%64==0.
// ---------------------------------------------------------------------------
template <bool OUT_F32>
__global__ __launch_bounds__(512, 2) void gemm_bt_bias_256(
    const s16* __restrict__ A,
    const s16* __restrict__ Bt,
    const float* __restrict__ bias,
    void* __restrict__ Cv,
    int M, int N, int K, int gx) {
    __shared__ __attribute__((aligned(16))) s16 As[2][256 * 64];
    __shared__ __attribute__((aligned(16))) s16 Bs[2][256 * 64];

    const int tid  = threadIdx.x;
    const int lane = tid & 63;
    const int wave = tid >> 6;   // 0..7
    const int l15  = lane & 15;
    const int quad = lane >> 4;
    const int wr   = wave >> 2;  // 0..1 (M half, 128 rows)
    const int wc   = wave & 3;   // 0..3 (N quarter, 64 cols)

    // T1: XCD-bijective swizzle (nwg % 8 == 0 for both call sites)
    const int cpx = (int)gridDim.x >> 3;
    const int bid = (int)blockIdx.x;
    const int swz = (bid & 7) * cpx + (bid >> 3);
    const int m0 = (swz / gx) * 256;
    const int n0 = (swz % gx) * 256;

    // staging: thread = (srow = tid>>3 of a 64-row chunk, granule tid&7);
    // source granule pre-swizzled (g ^ (row&7)); LDS dest linear (both-sides rule).
    const int srow = tid >> 3;
    const int sg   = (tid & 7) ^ (srow & 7);
    const s16* Ag = A  + (size_t)(m0 + srow) * K + sg * 8;
    const s16* Bg = Bt + (size_t)(n0 + srow) * K + sg * 8;

#define STG_A(buf, c, kt) load_lds16(Ag + (size_t)(c) * 64 * K + (size_t)(kt) * 64, \
                                     &As[buf][(c) * 4096 + wave * 512])
#define STG_B(buf, c, kt) load_lds16(Bg + (size_t)(c) * 64 * K + (size_t)(kt) * 64, \
                                     &Bs[buf][(c) * 4096 + wave * 512])

    f32x4 acc[8][4];
#pragma unroll
    for (int i = 0; i < 8; ++i)
#pragma unroll
        for (int j = 0; j < 4; ++j)
            acc[i][j] = (f32x4){0.f, 0.f, 0.f, 0.f};

    const int nk = K >> 6;

    // prologue: stage tile 0; wait B+A0,A2 (A1,A3 may fly until q2)
    STG_B(0, 0, 0); STG_B(0, 1, 0); STG_B(0, 2, 0); STG_B(0, 3, 0);
    STG_A(0, 0, 0); STG_A(0, 2, 0); STG_A(0, 1, 0); STG_A(0, 3, 0);
    asm volatile("s_waitcnt vmcnt(2)" ::: "memory");
    __builtin_amdgcn_s_barrier();

    for (int t = 0; t < nk; ++t) {
        const int buf  = t & 1;
        const int nbuf = buf ^ 1;
        const bool pre = (t + 1 < nk);
        bf16x8 bfr[4][2];  // B-frags held across the 4 phases of this K-tile
#pragma unroll
        for (int q = 0; q < 4; ++q) {
            if (q == 0) {
#pragma unroll
                for (int n = 0; n < 4; ++n)
#pragma unroll
                    for (int ks = 0; ks < 2; ++ks) {
                        const int br = wc * 64 + n * 16 + l15;
                        const int gs = ((ks * 4 + quad) ^ (l15 & 7)) * 8;
                        bfr[n][ks] = *(const bf16x8*)(&Bs[buf][br * 64 + gs]);
                    }
            }
            bf16x8 af[2][2];
#pragma unroll
            for (int i = 0; i < 2; ++i)
#pragma unroll
                for (int ks = 0; ks < 2; ++ks) {
                    const int ar = wr * 128 + (q * 2 + i) * 16 + l15;
                    const int gs = ((ks * 4 + quad) ^ (l15 & 7)) * 8;
                    af[i][ks] = *(const bf16x8*)(&As[buf][ar * 64 + gs]);
                }
            // next tile's staging: B at q0, A (chunk order 0,2,1,3) at q1
            if (q == 0 && pre) {
                STG_B(nbuf, 0, t + 1); STG_B(nbuf, 1, t + 1);
                STG_B(nbuf, 2, t + 1); STG_B(nbuf, 3, t + 1);
            }
            if (q == 1 && pre) {
                STG_A(nbuf, 0, t + 1); STG_A(nbuf, 2, t + 1);
                STG_A(nbuf, 1, t + 1); STG_A(nbuf, 3, t + 1);
            }
            __builtin_amdgcn_s_barrier();  // phase-align waves
            __builtin_amdgcn_s_setprio(1);
#pragma unroll
            for (int i = 0; i < 2; ++i)
#pragma unroll
                for (int n = 0; n < 4; ++n)
#pragma unroll
                    for (int ks = 0; ks < 2; ++ks)
                        acc[q * 2 + i][n] = __builtin_amdgcn_mfma_f32_16x16x32_bf16(
                            af[i][ks], bfr[n][ks], acc[q * 2 + i][n], 0, 0, 0);
            __builtin_amdgcn_s_setprio(0);
            // counted waits, always BEFORE the phase barrier (barrier collects all waves)
            if (q == 1) {  // this tile's A1,A3 must land before q2 reads them
                if (pre) asm volatile("s_waitcnt vmcnt(8)" ::: "memory");
                else     asm volatile("s_waitcnt vmcnt(0)" ::: "memory");
            }
            if (q == 3 && pre)  // boundary: next tile's B+A0,A2 (oldest 6 of 8) landed
                asm volatile("s_waitcnt vmcnt(2)" ::: "memory");
            __builtin_amdgcn_s_barrier();
        }
    }
#undef STG_A
#undef STG_B

    // epilogue: row-contiguous stores (4 back-to-back 32B segments per 128B line)
    float bv[4];
#pragma unroll
    for (int n = 0; n < 4; ++n)
        bv[n] = bias[n0 + wc * 64 + n * 16 + l15];
#pragma unroll
    for (int mf = 0; mf < 8; ++mf) {
#pragma unroll
        for (int r = 0; r < 4; ++r) {
            const int row = m0 + wr * 128 + mf * 16 + quad * 4 + r;
#pragma unroll
            for (int n = 0; n < 4; ++n) {
                const int col = n0 + wc * 64 + n * 16 + l15;
                const float v = acc[mf][n][r] + bv[n];
                if constexpr (OUT_F32)
                    ((float*)Cv)[(size_t)row * N + col] = v;
                else
                    ((s16*)Cv)[(size_t)row * N + col] = f2bf(v);
            }
        }
    }
}

// ---------------------------------------------------------------------------
// Flash attention (causal), fixed-M softmax, S^T formulation. (R10/R13/R14 proven)
// Flat grid of 1024 blocks = 4/CU resident. bid bits: hi=bid>>8 (CU-sharing round),
// bh=(bid>>2)&63, a=bid&3; qt = hi&1 ? 15-(2a+(hi>>1)) : 2a+(hi>>1).
// -> per-CU qt sets {x, 15-x, x+1, 14-x}: exactly 68 key-tile units per CU.
// ---------------------------------------------------------------------------
__global__ __launch_bounds__(256) void attn_fwd(
    const s16* __restrict__ qkv,
    s16* __restrict__ attn) {
    __shared__ __attribute__((aligned(16))) s16 Ks[64 * 72];
    __shared__ __attribute__((aligned(16))) s16 Vt[64 * 72];
    __shared__ __attribute__((aligned(16))) s16 PT[4][32][88];

    const int tid  = threadIdx.x;
    const int lane = tid & 63;
    const int wave = tid >> 6;
    const int l15  = lane & 15;
    const int quad = lane >> 4;

    // balanced (bh, qt) decomposition (see header comment)
    const int bid = blockIdx.x;
    const int hi  = bid >> 8;
    const int a   = bid & 3;
    const int bh  = (bid >> 2) & 63;
    const int qbase = a * 2 + (hi >> 1);
    const int qt  = (hi & 1) ? 15 - qbase : qbase;

    const size_t rowbase = (size_t)(bh >> 4) * 2048;
    const int hoff = (bh & 15) * 64;
    const int kp  = tid >> 3;  // 0..31: staged key-pair {2kp, 2kp+1}
    const int p_s = tid & 7;   // hd granule
    const int kg  = kp >> 2;   // key granule of this thread's pair

    const float C2 = 0.18033688011112042f;  // 0.125 * log2(e)
    const float M2 = 12.0f;                 // fixed shift (softmax shift-invariant)

    const int wq = qt * 128 + wave * 32;

    // Q fragments: lane holds Q[q = wq + qs*16 + l15][d = ks*32 + quad*8 + j]
    bf16x8 qf[2][2];
#pragma unroll
    for (int qs = 0; qs < 2; ++qs)
#pragma unroll
        for (int ks = 0; ks < 2; ++ks)
            qf[qs][ks] = *(const bf16x8*)(qkv + (rowbase + wq + qs * 16 + l15) * 3072 + hoff + ks * 32 + quad * 8);

    float l_lane[2] = {0.f, 0.f};
    f32x4 o[2][4];  // [qs][hs]; C-layout: q-col = l15, hd-row = hs*16 + quad*4 + r
#pragma unroll
    for (int qs = 0; qs < 2; ++qs)
#pragma unroll
        for (int hs = 0; hs < 4; ++hs)
            o[qs][hs] = (f32x4){0.f, 0.f, 0.f, 0.f};

    const int nkt = qt * 2 + 2;
    // prefetch tile 0 K/V
    bf16x8 kv[2], vv[2];
#pragma unroll
    for (int dk = 0; dk < 2; ++dk) {
        const s16* g = qkv + (rowbase + 2 * kp + dk) * 3072 + hoff + p_s * 8;
        kv[dk] = *(const bf16x8*)(g + 1024);
        vv[dk] = *(const bf16x8*)(g + 2048);
    }

    for (int kt = 0; kt < nkt; ++kt) {
        const int k0 = kt * 64;
        __syncthreads();  // prev iteration's LDS reads done
#pragma unroll
        for (int dk = 0; dk < 2; ++dk)  // K natural layout (R5-proven)
            *(bf16x8*)(Ks + (2 * kp + dk) * 72 + p_s * 8) = kv[dk];
#pragma unroll
        for (int j = 0; j < 8; ++j) {   // V^T swizzled, key-pair b32 (R7-verified)
            const unsigned dw = (unsigned)(unsigned short)vv[0][j] |
                                ((unsigned)(unsigned short)vv[1][j] << 16);
            *(unsigned*)(Vt + (p_s * 8 + j) * 72 + ((kg ^ p_s) << 3) + (2 * kp & 7)) = dw;
        }
        __syncthreads();

        if (kt + 1 < nkt) {  // prefetch next tile under compute
#pragma unroll
            for (int dk = 0; dk < 2; ++dk) {
                const s16* g = qkv + (rowbase + k0 + 64 + 2 * kp + dk) * 3072 + hoff + p_s * 8;
                kv[dk] = *(const bf16x8*)(g + 1024);
                vv[dk] = *(const bf16x8*)(g + 2048);
            }
        }

        if (k0 > wq + 31) continue;  // fully masked for this wave

        // S^T = K Q^T : st[qs][kb], key subtiles kb of 16
        f32x4 st[2][4];
#pragma unroll
        for (int qs = 0; qs < 2; ++qs)
#pragma unroll
            for (int kb = 0; kb < 4; ++kb)
                st[qs][kb] = (f32x4){0.f, 0.f, 0.f, 0.f};
        __builtin_amdgcn_s_setprio(1);
#pragma unroll
        for (int kb = 0; kb < 4; ++kb)
#pragma unroll
            for (int ks = 0; ks < 2; ++ks) {
                const bf16x8 kf = *(const bf16x8*)(Ks + (kb * 16 + l15) * 72 + ks * 32 + quad * 8);
#pragma unroll
                for (int qs = 0; qs < 2; ++qs)
                    st[qs][kb] = __builtin_amdgcn_mfma_f32_16x16x32_bf16(kf, qf[qs][ks], st[qs][kb], 0, 0, 0);
            }
        __builtin_amdgcn_s_setprio(0);

        // softmax (fixed-M) + P^T -> PT (b64, conflict-free)
        const bool edge = (k0 + 63 > wq);
#pragma unroll
        for (int qs = 0; qs < 2; ++qs) {
            const int q = wq + qs * 16 + l15;
#pragma unroll
            for (int kb = 0; kb < 4; ++kb) {
                float p4[4];
#pragma unroll
                for (int r = 0; r < 4; ++r) {
                    float t = fmaf(st[qs][kb][r], C2, -M2);
                    if (edge) {
                        const int key = k0 + kb * 16 + quad * 4 + r;
                        t = (key <= q) ? t : -150.f;  // exp2(-150) == 0
                    }
                    p4[r] = __builtin_amdgcn_exp2f(t);
                    l_lane[qs] += p4[r];
                }
                uint2 dd;
                dd.x = pack_bf16(p4[0], p4[1]);
                dd.y = pack_bf16(p4[2], p4[3]);
                *(uint2*)(&PT[wave][qs * 16 + l15][kb * 16 + quad * 4]) = dd;
            }
        }

        // O^T += V^T P^T
        __builtin_amdgcn_s_setprio(1);
#pragma unroll
        for (int kk = 0; kk < 2; ++kk) {
            bf16x8 pf[2];
#pragma unroll
            for (int qs = 0; qs < 2; ++qs)
                pf[qs] = *(const bf16x8*)(&PT[wave][qs * 16 + l15][kk * 32 + quad * 8]);
#pragma unroll
            for (int hs = 0; hs < 4; ++hs) {
                const bf16x8 vf = *(const bf16x8*)(
                    Vt + (hs * 16 + l15) * 72 + (((kk * 4 + quad) ^ (2 * hs + (l15 >> 3))) << 3));
#pragma unroll
                for (int qs = 0; qs < 2; ++qs)
                    o[qs][hs] = __builtin_amdgcn_mfma_f32_16x16x32_bf16(vf, pf[qs], o[qs][hs], 0, 0, 0);
            }
        }
        __builtin_amdgcn_s_setprio(0);
    }

    // l: sum across the 4 quads (lanes with same l15)
    float rl[2];
#pragma unroll
    for (int qs = 0; qs < 2; ++qs) {
        float l = l_lane[qs];
        l += __shfl_xor(l, 16);
        l += __shfl_xor(l, 32);
        rl[qs] = 1.f / l;
    }

    // epilogue: O^T[hd][q] -> attn[q][hoff+hd]; 4 consecutive hd per reg-quad -> b64
#pragma unroll
    for (int qs = 0; qs < 2; ++qs) {
        const int q = wq + qs * 16 + l15;
#pragma unroll
        for (int hs = 0; hs < 4; ++hs) {
            uint2 dd;
            dd.x = pack_bf16(o[qs][hs][0] * rl[qs], o[qs][hs][1] * rl[qs]);
            dd.y = pack_bf16(o[qs][hs][2] * rl[qs], o[qs][hs][3] * rl[qs]);
            *(uint2*)(attn + (rowbase + q) * 1024 + hoff + hs * 16 + quad * 4) = dd;
        }
    }
}

// ---------------------------------------------------------------------------
extern "C" void kernel_launch(void* const* d_in, const int* in_sizes, int n_in,
                              void* d_out, int out_size, void* d_ws, size_t ws_size,
                              hipStream_t stream) {
    const float* x    = (const float*)d_in[0];  // [8192,1024]
    const float* Wqkv = (const float*)d_in[1];  // [1024,3072]
    const float* bqkv = (const float*)d_in[2];  // [3072]
    const float* Wout = (const float*)d_in[3];  // [1024,1024]
    const float* bout = (const float*)d_in[4];  // [1024]
    float* out = (float*)d_out;                 // [8192,1024] fp32

    s16* ws   = (s16*)d_ws;
    s16* qkv  = ws;                          // [8192,3072] bf16
    s16* xba  = qkv + (size_t)8192 * 3072;   // [8192,1024] bf16: x-cast, later attn output
    s16* wtq  = xba + (size_t)8192 * 1024;   // [3072,1024] bf16
    s16* wto  = wtq + (size_t)3072 * 1024;   // [1024,1024] bf16

    cast_f32_bf16<<<8192, 256, 0, stream>>>(x, xba);
    transpose_cast<<<dim3(3072 / 32, 1024 / 32), dim3(32, 8), 0, stream>>>(Wqkv, wtq, 1024, 3072);
    transpose_cast<<<dim3(1024 / 32, 1024 / 32), dim3(32, 8), 0, stream>>>(Wout, wto, 1024, 1024);
    gemm_bt_bias_256<false><<<384, 512, 0, stream>>>(
        xba, wtq, bqkv, qkv, 8192, 3072, 1024, 12);
    attn_fwd<<<1024, 256, 0, stream>>>(qkv, xba);  // xba dead; reused as attn buf
    gemm_bt_bias_256<true><<<128, 512, 0, stream>>>(
        xba, wto, bout, out, 8192, 1024, 1024, 4);
}

// Round 9
// 261.466 us; speedup vs baseline: 1.1571x; 1.0498x over previous
//
#include <hip/hip_runtime.h>

// MultiHeadSelfAttention: B=4, S=2048, D=1024, H=16, HD=64, causal. fp32 I/O, bf16 MFMA.
// R17 = R16 attn (82 us) + geometry-fixed GEMMs. R16 datum: counted vmcnt NEUTRAL ->
// GEMM is LDS-read-BW bound (wave 128x64 = 24KB ds_read per 1 MFLOP -> 27% ceiling,
// matches MfmaUtil 26). Fixes:
//  1. QKV tile 256x384 (grid 32x8=256 = ONE balanced round; was 384 blocks = 2 rounds,
//     2nd half-empty). Wave tile 128x96 -> LDS-bytes/FLOP ratio ceiling 27% -> 35%.
//     OUT tile 256x128 -> grid 256 (was 128 = half chip idle).
//  2. Triple-buffer LDS (QKV 120KB, OUT 72KB; 1 blk/CU), 2-tile-deep prefetch:
//     stage t+2 -> compute t -> vmcnt(LOADS) [t+1 landed, issued a FULL tile ago = free]
//     -> ONE barrier/tile (was 8/tile). Never waits on fresh loads (T4).
//  3. BK=32 both-sides granule swizzle g^=(row>>1)&3 (bank-verified: 8 lanes per
//     4-bank slot x 8 slots = minimum-time b128, conflict-free; store side pre-swizzles
//     the global source granule, LDS dest stays linear for global_load_lds).
//  4. Transposes merged into one launch (6 -> 5 kernels).

typedef short s16;
typedef __attribute__((ext_vector_type(4))) short s16x4;
typedef __attribute__((ext_vector_type(8))) short bf16x8;
typedef __attribute__((ext_vector_type(4))) float f32x4;

__device__ __forceinline__ s16 f2bf(float f) {
    union { float f; unsigned int i; } v;
    v.f = f;
    unsigned int r = v.i + 0x7fffu + ((v.i >> 16) & 1u);  // RNE
    return (s16)(r >> 16);
}

// pack two fp32 -> bf16x2 dword (round-half-up)
__device__ __forceinline__ unsigned pack_bf16(float a, float b) {
    union { float f; unsigned u; } x, y;
    x.f = a; y.f = b;
    return __byte_perm(x.u + 0x8000u, y.u + 0x8000u, 0x7632);
}

__device__ __forceinline__ void load_lds16(const s16* g, s16* lds_base) {
    __builtin_amdgcn_global_load_lds(
        (const __attribute__((address_space(1))) void*)g,
        (__attribute__((address_space(3))) void*)lds_base, 16, 0, 0);
}

template <int N>
__device__ __forceinline__ void waitcnt_vm() {
    if constexpr (N == 0)      asm volatile("s_waitcnt vmcnt(0)" ::: "memory");
    else if constexpr (N == 3) asm volatile("s_waitcnt vmcnt(3)" ::: "memory");
    else if constexpr (N == 5) asm volatile("s_waitcnt vmcnt(5)" ::: "memory");
}

// ---------------------------------------------------------------------------
// fp32 -> bf16 elementwise cast
// ---------------------------------------------------------------------------
__global__ void cast_f32_bf16(const float* __restrict__ in, s16* __restrict__ out) {
    const int i = (blockIdx.x * 256 + threadIdx.x) * 4;
    const float4 f = *(const float4*)(in + i);
    s16x4 r = {f2bf(f.x), f2bf(f.y), f2bf(f.z), f2bf(f.w)};
    *(s16x4*)(out + i) = r;
}

// ---------------------------------------------------------------------------
// Merged transpose+cast for both weights: z=0 -> Wqkv [1024,3072], z=1 -> Wout
// [1024,1024] (blocks with bx>=32 idle-return). Body identical to proven version.
// ---------------------------------------------------------------------------
__global__ void transpose_cast2(const float* __restrict__ Wq, s16* __restrict__ oq,
                                const float* __restrict__ Wo, s16* __restrict__ oo) {
    __shared__ float tile[32][33];
    const float* in;
    s16* out;
    int C;
    if (blockIdx.z == 0) { in = Wq; out = oq; C = 3072; }
    else {
        if (blockIdx.x >= 32) return;  // whole block returns: no barrier divergence
        in = Wo; out = oo; C = 1024;
    }
    const int R = 1024;
    const int cb = blockIdx.x * 32, rb = blockIdx.y * 32;
    const int tx = threadIdx.x, ty = threadIdx.y;  // 32 x 8
#pragma unroll
    for (int i = 0; i < 32; i += 8)
        tile[ty + i][tx] = in[(size_t)(rb + ty + i) * C + cb + tx];
    __syncthreads();
#pragma unroll
    for (int i = 0; i < 32; i += 8)
        out[(size_t)(cb + ty + i) * R + rb + tx] = f2bf(tile[tx][ty + i]);
}

// ---------------------------------------------------------------------------
// C[M,N] = A[M,K] @ Bt[N,K]^T + bias[N]. A,Bt bf16; C fp32 or bf16.
// Tile BM=ACH*128 x BN=BCH*128, BK=32, 8 waves (NW_M x NW_N, NW_N=1<<NWN_L2).
// Wave out = MF*16 x NF*16. Triple-buffer LDS, 2-tile prefetch, 1 barrier/tile.
// Requires M%BM==0, N%BN==0, K%32==0, grid = (M/BM)*(N/BN) with grid%8==0.
// ---------------------------------------------------------------------------
template <bool OUT_F32, int ACH, int BCH, int NWN_L2, int MF, int NF>
__global__ __launch_bounds__(512, 2) void gemm_tb(
    const s16* __restrict__ A,
    const s16* __restrict__ Bt,
    const float* __restrict__ bias,
    void* __restrict__ Cv,
    int M, int N, int K, int gx) {
    constexpr int NWN   = 1 << NWN_L2;
    constexpr int LOADS = ACH + BCH;
    constexpr int ABUF  = ACH * 4096;  // elems per buffer (128 rows * 32 elem per chunk)
    constexpr int BBUF  = BCH * 4096;
    constexpr int BM = ACH * 128, BN = BCH * 128;
    static_assert(MF * 16 * (8 / NWN) == BM, "M geometry");
    static_assert(NF * 16 * NWN == BN, "N geometry");
    __shared__ __attribute__((aligned(16))) s16 As[3 * ABUF];
    __shared__ __attribute__((aligned(16))) s16 Bs[3 * BBUF];

    const int tid  = threadIdx.x;
    const int lane = tid & 63;
    const int wave = tid >> 6;           // 0..7
    const int l15  = lane & 15;
    const int quad = lane >> 4;
    const int wr   = wave >> NWN_L2;     // M group
    const int wc   = wave & (NWN - 1);   // N group

    // T1: XCD-bijective swizzle (grid % 8 == 0)
    const int cpx = (int)gridDim.x >> 3;
    const int bid = (int)blockIdx.x;
    const int swz = (bid & 7) * cpx + (bid >> 3);
    const int m0 = (swz / gx) * BM;
    const int n0 = (swz % gx) * BN;

    // staging map: thread = (row sr of a 128-row chunk, granule gl of 4x16B);
    // global granule pre-swizzled gl^((sr>>1)&3) (chunk-independent: 128%4==0 rows),
    // LDS dest linear (lane*16 within wave window) — both-sides rule.
    const int sr  = tid >> 2;            // 0..127
    const int gl  = tid & 3;
    const int gsw = gl ^ ((sr >> 1) & 3);
    const s16* Ag = A  + (size_t)(m0 + sr) * K + gsw * 8;
    const s16* Bg = Bt + (size_t)(n0 + sr) * K + gsw * 8;

#define STG(bufi, kt) do {                                                          \
    _Pragma("unroll")                                                               \
    for (int c = 0; c < ACH; ++c)                                                   \
        load_lds16(Ag + (size_t)c * 128 * K + (size_t)(kt) * 32,                    \
                   &As[(bufi) * ABUF + c * 4096 + wave * 512]);                     \
    _Pragma("unroll")                                                               \
    for (int c = 0; c < BCH; ++c)                                                   \
        load_lds16(Bg + (size_t)c * 128 * K + (size_t)(kt) * 32,                    \
                   &Bs[(bufi) * BBUF + c * 4096 + wave * 512]); } while (0)

    f32x4 acc[MF][NF];
#pragma unroll
    for (int i = 0; i < MF; ++i)
#pragma unroll
        for (int j = 0; j < NF; ++j)
            acc[i][j] = (f32x4){0.f, 0.f, 0.f, 0.f};

    const int nk = K >> 5;  // BK=32 tiles

    // prologue: stage tiles 0,1; wait for tile 0 (tile 1's LOADS stay in flight)
    STG(0, 0);
    STG(1, 1);
    waitcnt_vm<LOADS>();
    __builtin_amdgcn_s_barrier();

    for (int t = 0; t < nk; ++t) {
        const int cur = t % 3;
        if (t + 2 < nk) STG((t + 2) % 3, t + 2);  // 2-deep prefetch

        const s16* Ab = As + cur * ABUF;
        const s16* Bb = Bs + cur * BBUF;
        bf16x8 bf[NF];
#pragma unroll
        for (int nf = 0; nf < NF; ++nf) {
            const int row = wc * (NF * 16) + nf * 16 + l15;
            bf[nf] = *(const bf16x8*)(Bb + row * 32 + ((quad ^ ((row >> 1) & 3)) << 3));
        }
        __builtin_amdgcn_s_setprio(1);
#pragma unroll
        for (int mf = 0; mf < MF; ++mf) {
            const int row = wr * (MF * 16) + mf * 16 + l15;
            const bf16x8 af = *(const bf16x8*)(Ab + row * 32 + ((quad ^ ((row >> 1) & 3)) << 3));
#pragma unroll
            for (int nf = 0; nf < NF; ++nf)
                acc[mf][nf] = __builtin_amdgcn_mfma_f32_16x16x32_bf16(af, bf[nf], acc[mf][nf], 0, 0, 0);
        }
        __builtin_amdgcn_s_setprio(0);

        // wait: t+1's loads (issued one full tile ago) landed; t+2's stay in flight
        if (t + 2 < nk)      waitcnt_vm<LOADS>();
        else if (t + 1 < nk) waitcnt_vm<0>();
        if (t + 1 < nk) __builtin_amdgcn_s_barrier();
    }
#undef STG

    // epilogue: row-contiguous stores
    float bv[NF];
#pragma unroll
    for (int nf = 0; nf < NF; ++nf)
        bv[nf] = bias[n0 + wc * (NF * 16) + nf * 16 + l15];
#pragma unroll
    for (int mf = 0; mf < MF; ++mf) {
#pragma unroll
        for (int r = 0; r < 4; ++r) {
            const int row = m0 + wr * (MF * 16) + mf * 16 + quad * 4 + r;
#pragma unroll
            for (int nf = 0; nf < NF; ++nf) {
                const int col = n0 + wc * (NF * 16) + nf * 16 + l15;
                const float v = acc[mf][nf][r] + bv[nf];
                if constexpr (OUT_F32)
                    ((float*)Cv)[(size_t)row * N + col] = v;
                else
                    ((s16*)Cv)[(size_t)row * N + col] = f2bf(v);
            }
        }
    }
}

// ---------------------------------------------------------------------------
// Flash attention (causal), fixed-M softmax, S^T formulation. (R14/R16, 82 us proven)
// Flat grid of 1024 blocks = 4/CU resident. bid bits: hi=bid>>8 (CU-sharing round),
// bh=(bid>>2)&63, a=bid&3; qt = hi&1 ? 15-(2a+(hi>>1)) : 2a+(hi>>1).
// -> per-CU qt sets {x, 15-x, x+1, 14-x}: exactly 68 key-tile units per CU.
// ---------------------------------------------------------------------------
__global__ __launch_bounds__(256) void attn_fwd(
    const s16* __restrict__ qkv,
    s16* __restrict__ attn) {
    __shared__ __attribute__((aligned(16))) s16 Ks[64 * 72];
    __shared__ __attribute__((aligned(16))) s16 Vt[64 * 72];
    __shared__ __attribute__((aligned(16))) s16 PT[4][32][88];

    const int tid  = threadIdx.x;
    const int lane = tid & 63;
    const int wave = tid >> 6;
    const int l15  = lane & 15;
    const int quad = lane >> 4;

    // balanced (bh, qt) decomposition (see header comment)
    const int bid = blockIdx.x;
    const int hi  = bid >> 8;
    const int a   = bid & 3;
    const int bh  = (bid >> 2) & 63;
    const int qbase = a * 2 + (hi >> 1);
    const int qt  = (hi & 1) ? 15 - qbase : qbase;

    const size_t rowbase = (size_t)(bh >> 4) * 2048;
    const int hoff = (bh & 15) * 64;
    const int kp  = tid >> 3;  // 0..31: staged key-pair {2kp, 2kp+1}
    const int p_s = tid & 7;   // hd granule
    const int kg  = kp >> 2;   // key granule of this thread's pair

    const float C2 = 0.18033688011112042f;  // 0.125 * log2(e)
    const float M2 = 12.0f;                 // fixed shift (softmax shift-invariant)

    const int wq = qt * 128 + wave * 32;

    // Q fragments: lane holds Q[q = wq + qs*16 + l15][d = ks*32 + quad*8 + j]
    bf16x8 qf[2][2];
#pragma unroll
    for (int qs = 0; qs < 2; ++qs)
#pragma unroll
        for (int ks = 0; ks < 2; ++ks)
            qf[qs][ks] = *(const bf16x8*)(qkv + (rowbase + wq + qs * 16 + l15) * 3072 + hoff + ks * 32 + quad * 8);

    float l_lane[2] = {0.f, 0.f};
    f32x4 o[2][4];  // [qs][hs]; C-layout: q-col = l15, hd-row = hs*16 + quad*4 + r
#pragma unroll
    for (int qs = 0; qs < 2; ++qs)
#pragma unroll
        for (int hs = 0; hs < 4; ++hs)
            o[qs][hs] = (f32x4){0.f, 0.f, 0.f, 0.f};

    const int nkt = qt * 2 + 2;
    // prefetch tile 0 K/V
    bf16x8 kv[2], vv[2];
#pragma unroll
    for (int dk = 0; dk < 2; ++dk) {
        const s16* g = qkv + (rowbase + 2 * kp + dk) * 3072 + hoff + p_s * 8;
        kv[dk] = *(const bf16x8*)(g + 1024);
        vv[dk] = *(const bf16x8*)(g + 2048);
    }

    for (int kt = 0; kt < nkt; ++kt) {
        const int k0 = kt * 64;
        __syncthreads();  // prev iteration's LDS reads done
#pragma unroll
        for (int dk = 0; dk < 2; ++dk)  // K natural layout (R5-proven)
            *(bf16x8*)(Ks + (2 * kp + dk) * 72 + p_s * 8) = kv[dk];
#pragma unroll
        for (int j = 0; j < 8; ++j) {   // V^T swizzled, key-pair b32 (R7-verified)
            const unsigned dw = (unsigned)(unsigned short)vv[0][j] |
                                ((unsigned)(unsigned short)vv[1][j] << 16);
            *(unsigned*)(Vt + (p_s * 8 + j) * 72 + ((kg ^ p_s) << 3) + (2 * kp & 7)) = dw;
        }
        __syncthreads();

        if (kt + 1 < nkt) {  // prefetch next tile under compute
#pragma unroll
            for (int dk = 0; dk < 2; ++dk) {
                const s16* g = qkv + (rowbase + k0 + 64 + 2 * kp + dk) * 3072 + hoff + p_s * 8;
                kv[dk] = *(const bf16x8*)(g + 1024);
                vv[dk] = *(const bf16x8*)(g + 2048);
            }
        }

        if (k0 > wq + 31) continue;  // fully masked for this wave

        // S^T = K Q^T : st[qs][kb], key subtiles kb of 16
        f32x4 st[2][4];
#pragma unroll
        for (int qs = 0; qs < 2; ++qs)
#pragma unroll
            for (int kb = 0; kb < 4; ++kb)
                st[qs][kb] = (f32x4){0.f, 0.f, 0.f, 0.f};
        __builtin_amdgcn_s_setprio(1);
#pragma unroll
        for (int kb = 0; kb < 4; ++kb)
#pragma unroll
            for (int ks = 0; ks < 2; ++ks) {
                const bf16x8 kf = *(const bf16x8*)(Ks + (kb * 16 + l15) * 72 + ks * 32 + quad * 8);
#pragma unroll
                for (int qs = 0; qs < 2; ++qs)
                    st[qs][kb] = __builtin_amdgcn_mfma_f32_16x16x32_bf16(kf, qf[qs][ks], st[qs][kb], 0, 0, 0);
            }
        __builtin_amdgcn_s_setprio(0);

        // softmax (fixed-M) + P^T -> PT (b64, conflict-free)
        const bool edge = (k0 + 63 > wq);
#pragma unroll
        for (int qs = 0; qs < 2; ++qs) {
            const int q = wq + qs * 16 + l15;
#pragma unroll
            for (int kb = 0; kb < 4; ++kb) {
                float p4[4];
#pragma unroll
                for (int r = 0; r < 4; ++r) {
                    float t = fmaf(st[qs][kb][r], C2, -M2);
                    if (edge) {
                        const int key = k0 + kb * 16 + quad * 4 + r;
                        t = (key <= q) ? t : -150.f;  // exp2(-150) == 0
                    }
                    p4[r] = __builtin_amdgcn_exp2f(t);
                    l_lane[qs] += p4[r];
                }
                uint2 dd;
                dd.x = pack_bf16(p4[0], p4[1]);
                dd.y = pack_bf16(p4[2], p4[3]);
                *(uint2*)(&PT[wave][qs * 16 + l15][kb * 16 + quad * 4]) = dd;
            }
        }

        // O^T += V^T P^T
        __builtin_amdgcn_s_setprio(1);
#pragma unroll
        for (int kk = 0; kk < 2; ++kk) {
            bf16x8 pf[2];
#pragma unroll
            for (int qs = 0; qs < 2; ++qs)
                pf[qs] = *(const bf16x8*)(&PT[wave][qs * 16 + l15][kk * 32 + quad * 8]);
#pragma unroll
            for (int hs = 0; hs < 4; ++hs) {
                const bf16x8 vf = *(const bf16x8*)(
                    Vt + (hs * 16 + l15) * 72 + (((kk * 4 + quad) ^ (2 * hs + (l15 >> 3))) << 3));
#pragma unroll
                for (int qs = 0; qs < 2; ++qs)
                    o[qs][hs] = __builtin_amdgcn_mfma_f32_16x16x32_bf16(vf, pf[qs], o[qs][hs], 0, 0, 0);
            }
        }
        __builtin_amdgcn_s_setprio(0);
    }

    // l: sum across the 4 quads (lanes with same l15)
    float rl[2];
#pragma unroll
    for (int qs = 0; qs < 2; ++qs) {
        float l = l_lane[qs];
        l += __shfl_xor(l, 16);
        l += __shfl_xor(l, 32);
        rl[qs] = 1.f / l;
    }

    // epilogue: O^T[hd][q] -> attn[q][hoff+hd]; 4 consecutive hd per reg-quad -> b64
#pragma unroll
    for (int qs = 0; qs < 2; ++qs) {
        const int q = wq + qs * 16 + l15;
#pragma unroll
        for (int hs = 0; hs < 4; ++hs) {
            uint2 dd;
            dd.x = pack_bf16(o[qs][hs][0] * rl[qs], o[qs][hs][1] * rl[qs]);
            dd.y = pack_bf16(o[qs][hs][2] * rl[qs], o[qs][hs][3] * rl[qs]);
            *(uint2*)(attn + (rowbase + q) * 1024 + hoff + hs * 16 + quad * 4) = dd;
        }
    }
}

// ---------------------------------------------------------------------------
extern "C" void kernel_launch(void* const* d_in, const int* in_sizes, int n_in,
                              void* d_out, int out_size, void* d_ws, size_t ws_size,
                              hipStream_t stream) {
    const float* x    = (const float*)d_in[0];  // [8192,1024]
    const float* Wqkv = (const float*)d_in[1];  // [1024,3072]
    const float* bqkv = (const float*)d_in[2];  // [3072]
    const float* Wout = (const float*)d_in[3];  // [1024,1024]
    const float* bout = (const float*)d_in[4];  // [1024]
    float* out = (float*)d_out;                 // [8192,1024] fp32

    s16* ws   = (s16*)d_ws;
    s16* qkv  = ws;                          // [8192,3072] bf16
    s16* xba  = qkv + (size_t)8192 * 3072;   // [8192,1024] bf16: x-cast, later attn output
    s16* wtq  = xba + (size_t)8192 * 1024;   // [3072,1024] bf16
    s16* wto  = wtq + (size_t)3072 * 1024;   // [1024,1024] bf16

    cast_f32_bf16<<<8192, 256, 0, stream>>>(x, xba);
    transpose_cast2<<<dim3(96, 32, 2), dim3(32, 8), 0, stream>>>(Wqkv, wtq, Wout, wto);
    // QKV: 256x384 tile, grid (3072/384)x(8192/256) = 8x32 = 256 blocks (one round)
    gemm_tb<false, 2, 3, 2, 8, 6><<<256, 512, 0, stream>>>(
        xba, wtq, bqkv, qkv, 8192, 3072, 1024, 8);
    attn_fwd<<<1024, 256, 0, stream>>>(qkv, xba);  // xba dead; reused as attn buf
    // OUT: 256x128 tile, grid (1024/128)x(8192/256) = 8x32 = 256 blocks (one round)
    gemm_tb<true, 2, 1, 1, 4, 4><<<256, 512, 0, stream>>>(
        xba, wto, bout, out, 8192, 1024, 1024, 8);
}

// Round 10
// 258.611 us; speedup vs baseline: 1.1699x; 1.0110x over previous
//
#include <hip/hip_runtime.h>

// MultiHeadSelfAttention: B=4, S=2048, D=1024, H=16, HD=64, causal. fp32 I/O, bf16 MFMA.
// R18 = R17 with prep fused into ONE kernel (5 -> 4 launches). GAP-THEORY EXPERIMENT:
// kernel-time accounting (attn 81 + QKV ~58 + OUT ~25 + prep ~12 = ~176) leaves ~85 us
// unexplained in every round regardless of GEMM structure -> suspected inter-dispatch
// gaps (~12-15 us x launches). Fusing cast+transposeQ+transposeO into a flat-grid
// kernel (block-range switch, per-block uniform) removes one gap while leaving kernel
// time ~unchanged: any total delta isolates the gap size. GEMMs/attn byte-identical
// to R17 (proven: QKV 256x384 BK=32 triple-buffer 2-deep prefetch, wave 128x96;
// OUT 256x128; attn balanced 1024-block, 82 us).

typedef short s16;
typedef __attribute__((ext_vector_type(4))) short s16x4;
typedef __attribute__((ext_vector_type(8))) short bf16x8;
typedef __attribute__((ext_vector_type(4))) float f32x4;

__device__ __forceinline__ s16 f2bf(float f) {
    union { float f; unsigned int i; } v;
    v.f = f;
    unsigned int r = v.i + 0x7fffu + ((v.i >> 16) & 1u);  // RNE
    return (s16)(r >> 16);
}

// pack two fp32 -> bf16x2 dword (round-half-up)
__device__ __forceinline__ unsigned pack_bf16(float a, float b) {
    union { float f; unsigned u; } x, y;
    x.f = a; y.f = b;
    return __byte_perm(x.u + 0x8000u, y.u + 0x8000u, 0x7632);
}

__device__ __forceinline__ void load_lds16(const s16* g, s16* lds_base) {
    __builtin_amdgcn_global_load_lds(
        (const __attribute__((address_space(1))) void*)g,
        (__attribute__((address_space(3))) void*)lds_base, 16, 0, 0);
}

template <int N>
__device__ __forceinline__ void waitcnt_vm() {
    if constexpr (N == 0)      asm volatile("s_waitcnt vmcnt(0)" ::: "memory");
    else if constexpr (N == 3) asm volatile("s_waitcnt vmcnt(3)" ::: "memory");
    else if constexpr (N == 5) asm volatile("s_waitcnt vmcnt(5)" ::: "memory");
}

// ---------------------------------------------------------------------------
// Fused prep: cast x (blocks 0..8191), transpose Wqkv (8192..11263, 96x32),
// transpose Wout (11264..12287, 32x32). Per-block uniform branch; bodies are the
// R17-proven cast/transpose implementations.
// ---------------------------------------------------------------------------
__global__ __launch_bounds__(256) void prep(
    const float* __restrict__ x,    s16* __restrict__ xo,
    const float* __restrict__ Wq,   s16* __restrict__ oq,
    const float* __restrict__ Wo,   s16* __restrict__ oo) {
    const int bid = blockIdx.x;
    const int tid = threadIdx.x;
    if (bid < 8192) {
        const int i = (bid * 256 + tid) * 4;
        const float4 f = *(const float4*)(x + i);
        s16x4 r = {f2bf(f.x), f2bf(f.y), f2bf(f.z), f2bf(f.w)};
        *(s16x4*)(xo + i) = r;
        return;
    }
    __shared__ float tile[32][33];
    const float* in;
    s16* out;
    int C, bx, by;
    if (bid < 11264) {
        const int b = bid - 8192;
        in = Wq; out = oq; C = 3072; bx = b % 96; by = b / 96;
    } else {
        const int b = bid - 11264;
        in = Wo; out = oo; C = 1024; bx = b & 31; by = b >> 5;
    }
    const int R = 1024;
    const int cb = bx * 32, rb = by * 32;
    const int tx = tid & 31, ty = tid >> 5;  // 32 x 8
#pragma unroll
    for (int i = 0; i < 32; i += 8)
        tile[ty + i][tx] = in[(size_t)(rb + ty + i) * C + cb + tx];
    __syncthreads();
#pragma unroll
    for (int i = 0; i < 32; i += 8)
        out[(size_t)(cb + ty + i) * R + rb + tx] = f2bf(tile[tx][ty + i]);
}

// ---------------------------------------------------------------------------
// C[M,N] = A[M,K] @ Bt[N,K]^T + bias[N]. A,Bt bf16; C fp32 or bf16.
// Tile BM=ACH*128 x BN=BCH*128, BK=32, 8 waves (NW_M x NW_N, NW_N=1<<NWN_L2).
// Wave out = MF*16 x NF*16. Triple-buffer LDS, 2-tile prefetch, 1 barrier/tile.
// Requires M%BM==0, N%BN==0, K%32==0, grid = (M/BM)*(N/BN) with grid%8==0.
// (R17, correctness-proven)
// ---------------------------------------------------------------------------
template <bool OUT_F32, int ACH, int BCH, int NWN_L2, int MF, int NF>
__global__ __launch_bounds__(512, 2) void gemm_tb(
    const s16* __restrict__ A,
    const s16* __restrict__ Bt,
    const float* __restrict__ bias,
    void* __restrict__ Cv,
    int M, int N, int K, int gx) {
    constexpr int NWN   = 1 << NWN_L2;
    constexpr int LOADS = ACH + BCH;
    constexpr int ABUF  = ACH * 4096;  // elems per buffer (128 rows * 32 elem per chunk)
    constexpr int BBUF  = BCH * 4096;
    constexpr int BM = ACH * 128, BN = BCH * 128;
    static_assert(MF * 16 * (8 / NWN) == BM, "M geometry");
    static_assert(NF * 16 * NWN == BN, "N geometry");
    __shared__ __attribute__((aligned(16))) s16 As[3 * ABUF];
    __shared__ __attribute__((aligned(16))) s16 Bs[3 * BBUF];

    const int tid  = threadIdx.x;
    const int lane = tid & 63;
    const int wave = tid >> 6;           // 0..7
    const int l15  = lane & 15;
    const int quad = lane >> 4;
    const int wr   = wave >> NWN_L2;     // M group
    const int wc   = wave & (NWN - 1);   // N group

    // T1: XCD-bijective swizzle (grid % 8 == 0)
    const int cpx = (int)gridDim.x >> 3;
    const int bid = (int)blockIdx.x;
    const int swz = (bid & 7) * cpx + (bid >> 3);
    const int m0 = (swz / gx) * BM;
    const int n0 = (swz % gx) * BN;

    // staging map: thread = (row sr of a 128-row chunk, granule gl of 4x16B);
    // global granule pre-swizzled gl^((sr>>1)&3) (chunk-independent: 128%4==0 rows),
    // LDS dest linear (lane*16 within wave window) — both-sides rule.
    const int sr  = tid >> 2;            // 0..127
    const int gl  = tid & 3;
    const int gsw = gl ^ ((sr >> 1) & 3);
    const s16* Ag = A  + (size_t)(m0 + sr) * K + gsw * 8;
    const s16* Bg = Bt + (size_t)(n0 + sr) * K + gsw * 8;

#define STG(bufi, kt) do {                                                          \
    _Pragma("unroll")                                                               \
    for (int c = 0; c < ACH; ++c)                                                   \
        load_lds16(Ag + (size_t)c * 128 * K + (size_t)(kt) * 32,                    \
                   &As[(bufi) * ABUF + c * 4096 + wave * 512]);                     \
    _Pragma("unroll")                                                               \
    for (int c = 0; c < BCH; ++c)                                                   \
        load_lds16(Bg + (size_t)c * 128 * K + (size_t)(kt) * 32,                    \
                   &Bs[(bufi) * BBUF + c * 4096 + wave * 512]); } while (0)

    f32x4 acc[MF][NF];
#pragma unroll
    for (int i = 0; i < MF; ++i)
#pragma unroll
        for (int j = 0; j < NF; ++j)
            acc[i][j] = (f32x4){0.f, 0.f, 0.f, 0.f};

    const int nk = K >> 5;  // BK=32 tiles

    // prologue: stage tiles 0,1; wait for tile 0 (tile 1's LOADS stay in flight)
    STG(0, 0);
    STG(1, 1);
    waitcnt_vm<LOADS>();
    __builtin_amdgcn_s_barrier();

    for (int t = 0; t < nk; ++t) {
        const int cur = t % 3;
        if (t + 2 < nk) STG((t + 2) % 3, t + 2);  // 2-deep prefetch

        const s16* Ab = As + cur * ABUF;
        const s16* Bb = Bs + cur * BBUF;
        bf16x8 bf[NF];
#pragma unroll
        for (int nf = 0; nf < NF; ++nf) {
            const int row = wc * (NF * 16) + nf * 16 + l15;
            bf[nf] = *(const bf16x8*)(Bb + row * 32 + ((quad ^ ((row >> 1) & 3)) << 3));
        }
        __builtin_amdgcn_s_setprio(1);
#pragma unroll
        for (int mf = 0; mf < MF; ++mf) {
            const int row = wr * (MF * 16) + mf * 16 + l15;
            const bf16x8 af = *(const bf16x8*)(Ab + row * 32 + ((quad ^ ((row >> 1) & 3)) << 3));
#pragma unroll
            for (int nf = 0; nf < NF; ++nf)
                acc[mf][nf] = __builtin_amdgcn_mfma_f32_16x16x32_bf16(af, bf[nf], acc[mf][nf], 0, 0, 0);
        }
        __builtin_amdgcn_s_setprio(0);

        // wait: t+1's loads (issued one full tile ago) landed; t+2's stay in flight
        if (t + 2 < nk)      waitcnt_vm<LOADS>();
        else if (t + 1 < nk) waitcnt_vm<0>();
        if (t + 1 < nk) __builtin_amdgcn_s_barrier();
    }
#undef STG

    // epilogue: row-contiguous stores
    float bv[NF];
#pragma unroll
    for (int nf = 0; nf < NF; ++nf)
        bv[nf] = bias[n0 + wc * (NF * 16) + nf * 16 + l15];
#pragma unroll
    for (int mf = 0; mf < MF; ++mf) {
#pragma unroll
        for (int r = 0; r < 4; ++r) {
            const int row = m0 + wr * (MF * 16) + mf * 16 + quad * 4 + r;
#pragma unroll
            for (int nf = 0; nf < NF; ++nf) {
                const int col = n0 + wc * (NF * 16) + nf * 16 + l15;
                const float v = acc[mf][nf][r] + bv[nf];
                if constexpr (OUT_F32)
                    ((float*)Cv)[(size_t)row * N + col] = v;
                else
                    ((s16*)Cv)[(size_t)row * N + col] = f2bf(v);
            }
        }
    }
}

// ---------------------------------------------------------------------------
// Flash attention (causal), fixed-M softmax, S^T formulation. (R14/R16/R17 proven)
// Flat grid of 1024 blocks = 4/CU resident. bid bits: hi=bid>>8 (CU-sharing round),
// bh=(bid>>2)&63, a=bid&3; qt = hi&1 ? 15-(2a+(hi>>1)) : 2a+(hi>>1).
// -> per-CU qt sets {x, 15-x, x+1, 14-x}: exactly 68 key-tile units per CU.
// ---------------------------------------------------------------------------
__global__ __launch_bounds__(256) void attn_fwd(
    const s16* __restrict__ qkv,
    s16* __restrict__ attn) {
    __shared__ __attribute__((aligned(16))) s16 Ks[64 * 72];
    __shared__ __attribute__((aligned(16))) s16 Vt[64 * 72];
    __shared__ __attribute__((aligned(16))) s16 PT[4][32][88];

    const int tid  = threadIdx.x;
    const int lane = tid & 63;
    const int wave = tid >> 6;
    const int l15  = lane & 15;
    const int quad = lane >> 4;

    // balanced (bh, qt) decomposition (see header comment)
    const int bid = blockIdx.x;
    const int hi  = bid >> 8;
    const int a   = bid & 3;
    const int bh  = (bid >> 2) & 63;
    const int qbase = a * 2 + (hi >> 1);
    const int qt  = (hi & 1) ? 15 - qbase : qbase;

    const size_t rowbase = (size_t)(bh >> 4) * 2048;
    const int hoff = (bh & 15) * 64;
    const int kp  = tid >> 3;  // 0..31: staged key-pair {2kp, 2kp+1}
    const int p_s = tid & 7;   // hd granule
    const int kg  = kp >> 2;   // key granule of this thread's pair

    const float C2 = 0.18033688011112042f;  // 0.125 * log2(e)
    const float M2 = 12.0f;                 // fixed shift (softmax shift-invariant)

    const int wq = qt * 128 + wave * 32;

    // Q fragments: lane holds Q[q = wq + qs*16 + l15][d = ks*32 + quad*8 + j]
    bf16x8 qf[2][2];
#pragma unroll
    for (int qs = 0; qs < 2; ++qs)
#pragma unroll
        for (int ks = 0; ks < 2; ++ks)
            qf[qs][ks] = *(const bf16x8*)(qkv + (rowbase + wq + qs * 16 + l15) * 3072 + hoff + ks * 32 + quad * 8);

    float l_lane[2] = {0.f, 0.f};
    f32x4 o[2][4];  // [qs][hs]; C-layout: q-col = l15, hd-row = hs*16 + quad*4 + r
#pragma unroll
    for (int qs = 0; qs < 2; ++qs)
#pragma unroll
        for (int hs = 0; hs < 4; ++hs)
            o[qs][hs] = (f32x4){0.f, 0.f, 0.f, 0.f};

    const int nkt = qt * 2 + 2;
    // prefetch tile 0 K/V
    bf16x8 kv[2], vv[2];
#pragma unroll
    for (int dk = 0; dk < 2; ++dk) {
        const s16* g = qkv + (rowbase + 2 * kp + dk) * 3072 + hoff + p_s * 8;
        kv[dk] = *(const bf16x8*)(g + 1024);
        vv[dk] = *(const bf16x8*)(g + 2048);
    }

    for (int kt = 0; kt < nkt; ++kt) {
        const int k0 = kt * 64;
        __syncthreads();  // prev iteration's LDS reads done
#pragma unroll
        for (int dk = 0; dk < 2; ++dk)  // K natural layout (R5-proven)
            *(bf16x8*)(Ks + (2 * kp + dk) * 72 + p_s * 8) = kv[dk];
#pragma unroll
        for (int j = 0; j < 8; ++j) {   // V^T swizzled, key-pair b32 (R7-verified)
            const unsigned dw = (unsigned)(unsigned short)vv[0][j] |
                                ((unsigned)(unsigned short)vv[1][j] << 16);
            *(unsigned*)(Vt + (p_s * 8 + j) * 72 + ((kg ^ p_s) << 3) + (2 * kp & 7)) = dw;
        }
        __syncthreads();

        if (kt + 1 < nkt) {  // prefetch next tile under compute
#pragma unroll
            for (int dk = 0; dk < 2; ++dk) {
                const s16* g = qkv + (rowbase + k0 + 64 + 2 * kp + dk) * 3072 + hoff + p_s * 8;
                kv[dk] = *(const bf16x8*)(g + 1024);
                vv[dk] = *(const bf16x8*)(g + 2048);
            }
        }

        if (k0 > wq + 31) continue;  // fully masked for this wave

        // S^T = K Q^T : st[qs][kb], key subtiles kb of 16
        f32x4 st[2][4];
#pragma unroll
        for (int qs = 0; qs < 2; ++qs)
#pragma unroll
            for (int kb = 0; kb < 4; ++kb)
                st[qs][kb] = (f32x4){0.f, 0.f, 0.f, 0.f};
        __builtin_amdgcn_s_setprio(1);
#pragma unroll
        for (int kb = 0; kb < 4; ++kb)
#pragma unroll
            for (int ks = 0; ks < 2; ++ks) {
                const bf16x8 kf = *(const bf16x8*)(Ks + (kb * 16 + l15) * 72 + ks * 32 + quad * 8);
#pragma unroll
                for (int qs = 0; qs < 2; ++qs)
                    st[qs][kb] = __builtin_amdgcn_mfma_f32_16x16x32_bf16(kf, qf[qs][ks], st[qs][kb], 0, 0, 0);
            }
        __builtin_amdgcn_s_setprio(0);

        // softmax (fixed-M) + P^T -> PT (b64, conflict-free)
        const bool edge = (k0 + 63 > wq);
#pragma unroll
        for (int qs = 0; qs < 2; ++qs) {
            const int q = wq + qs * 16 + l15;
#pragma unroll
            for (int kb = 0; kb < 4; ++kb) {
                float p4[4];
#pragma unroll
                for (int r = 0; r < 4; ++r) {
                    float t = fmaf(st[qs][kb][r], C2, -M2);
                    if (edge) {
                        const int key = k0 + kb * 16 + quad * 4 + r;
                        t = (key <= q) ? t : -150.f;  // exp2(-150) == 0
                    }
                    p4[r] = __builtin_amdgcn_exp2f(t);
                    l_lane[qs] += p4[r];
                }
                uint2 dd;
                dd.x = pack_bf16(p4[0], p4[1]);
                dd.y = pack_bf16(p4[2], p4[3]);
                *(uint2*)(&PT[wave][qs * 16 + l15][kb * 16 + quad * 4]) = dd;
            }
        }

        // O^T += V^T P^T
        __builtin_amdgcn_s_setprio(1);
#pragma unroll
        for (int kk = 0; kk < 2; ++kk) {
            bf16x8 pf[2];
#pragma unroll
            for (int qs = 0; qs < 2; ++qs)
                pf[qs] = *(const bf16x8*)(&PT[wave][qs * 16 + l15][kk * 32 + quad * 8]);
#pragma unroll
            for (int hs = 0; hs < 4; ++hs) {
                const bf16x8 vf = *(const bf16x8*)(
                    Vt + (hs * 16 + l15) * 72 + (((kk * 4 + quad) ^ (2 * hs + (l15 >> 3))) << 3));
#pragma unroll
                for (int qs = 0; qs < 2; ++qs)
                    o[qs][hs] = __builtin_amdgcn_mfma_f32_16x16x32_bf16(vf, pf[qs], o[qs][hs], 0, 0, 0);
            }
        }
        __builtin_amdgcn_s_setprio(0);
    }

    // l: sum across the 4 quads (lanes with same l15)
    float rl[2];
#pragma unroll
    for (int qs = 0; qs < 2; ++qs) {
        float l = l_lane[qs];
        l += __shfl_xor(l, 16);
        l += __shfl_xor(l, 32);
        rl[qs] = 1.f / l;
    }

    // epilogue: O^T[hd][q] -> attn[q][hoff+hd]; 4 consecutive hd per reg-quad -> b64
#pragma unroll
    for (int qs = 0; qs < 2; ++qs) {
        const int q = wq + qs * 16 + l15;
#pragma unroll
        for (int hs = 0; hs < 4; ++hs) {
            uint2 dd;
            dd.x = pack_bf16(o[qs][hs][0] * rl[qs], o[qs][hs][1] * rl[qs]);
            dd.y = pack_bf16(o[qs][hs][2] * rl[qs], o[qs][hs][3] * rl[qs]);
            *(uint2*)(attn + (rowbase + q) * 1024 + hoff + hs * 16 + quad * 4) = dd;
        }
    }
}

// ---------------------------------------------------------------------------
extern "C" void kernel_launch(void* const* d_in, const int* in_sizes, int n_in,
                              void* d_out, int out_size, void* d_ws, size_t ws_size,
                              hipStream_t stream) {
    const float* x    = (const float*)d_in[0];  // [8192,1024]
    const float* Wqkv = (const float*)d_in[1];  // [1024,3072]
    const float* bqkv = (const float*)d_in[2];  // [3072]
    const float* Wout = (const float*)d_in[3];  // [1024,1024]
    const float* bout = (const float*)d_in[4];  // [1024]
    float* out = (float*)d_out;                 // [8192,1024] fp32

    s16* ws   = (s16*)d_ws;
    s16* qkv  = ws;                          // [8192,3072] bf16
    s16* xba  = qkv + (size_t)8192 * 3072;   // [8192,1024] bf16: x-cast, later attn output
    s16* wtq  = xba + (size_t)8192 * 1024;   // [3072,1024] bf16
    s16* wto  = wtq + (size_t)3072 * 1024;   // [1024,1024] bf16

    prep<<<12288, 256, 0, stream>>>(x, xba, Wqkv, wtq, Wout, wto);
    // QKV: 256x384 tile, grid (3072/384)x(8192/256) = 8x32 = 256 blocks (one round)
    gemm_tb<false, 2, 3, 2, 8, 6><<<256, 512, 0, stream>>>(
        xba, wtq, bqkv, qkv, 8192, 3072, 1024, 8);
    attn_fwd<<<1024, 256, 0, stream>>>(qkv, xba);  // xba dead; reused as attn buf
    // OUT: 256x128 tile, grid (1024/128)x(8192/256) = 8x32 = 256 blocks (one round)
    gemm_tb<true, 2, 1, 1, 4, 4><<<256, 512, 0, stream>>>(
        xba, wto, bout, out, 8192, 1024, 1024, 8);
}